// Round 3
// baseline (147.484 us; speedup 1.0000x reference)
//
#include <hip/hip_runtime.h>
#include <hip/hip_bf16.h>

typedef __bf16 bf16x8 __attribute__((ext_vector_type(8)));
typedef float  f32x4  __attribute__((ext_vector_type(4)));

#define MFMA(a, b, c) __builtin_amdgcn_mfma_f32_16x16x32_bf16((a), (b), (c), 0, 0, 0)

// Tile: 64 edges per block-iteration. D=128, H=64, K=8 (padded to 16 in MFMA N).
// LDS: xh [64][128] bf16 (16KB) + xl (16KB) + H f32 [64][64] (16KB) = 48KB -> 3 blocks/CU.
// XOR swizzle byte ^= (row&7)<<4 kills the 16-way ds_read_b128 bank conflict.
//
// R3 restructure (LDS-pipe was the bottleneck, ~3700 cyc/tile vs HBM 3140):
//  - m-split: wave wid owns edge rows [wid*16,+16). Its 8 A-frag ds_reads are
//    shared across all 4 n-tiles of w1 (was 4x redundant across waves) AND
//    reused from registers for x@w_proj (was 8 more reads). 160 -> 40 b128/tile.
//  - HF rows are same-wave write->read: one barrier deleted (2/tile).
//  - 2-pass split-bf16 on w1/wp (drop x_hi@w_lo), 3-pass kept on w2.
//  - softmax without max-subtract (logits bounded, f32 exp exact enough):
//    12 fewer shuffles/wave; sum+dot reduced together.

__device__ __forceinline__ int swz(int row, int byteInRow) {
    return row * 256 + (byteInRow ^ ((row & 7) << 4));
}

__global__ __launch_bounds__(256, 3) void edge_moe_kernel(
    const float* __restrict__ x,  const float* __restrict__ w1,
    const float* __restrict__ b1, const float* __restrict__ w2,
    const float* __restrict__ b2, const float* __restrict__ wp,
    float* __restrict__ outFused, float* __restrict__ outAlpha, int E)
{
    __shared__ __align__(16) char lds[49152];
    char* XH = lds;
    char* XL = lds + 16384;
    char* HF = lds + 32768;

    const int tid  = threadIdx.x;
    const int lane = tid & 63;
    const int wid  = tid >> 6;   // wave id 0..3 = edge-row tile owner
    const int lc   = lane & 15;  // fragment col / row index
    const int lg   = lane >> 4;  // k-group 0..3

    // ---- Weight B-fragments in registers ----
    // B-frag (16x16x32): lane holds B[k = kk*32 + lg*8 + j][n], j=0..7.
    bf16x8 w1h[4][4];            // [kk][nt], n = nt*16+lc  (bf16-rounded, 2-pass)
#pragma unroll
    for (int kk = 0; kk < 4; ++kk)
#pragma unroll
        for (int nt = 0; nt < 4; ++nt) {
            bf16x8 h;
#pragma unroll
            for (int j = 0; j < 8; ++j) {
                int kidx = kk * 32 + lg * 8 + j;
                h[j] = (__bf16)w1[kidx * 64 + nt * 16 + lc];
            }
            w1h[kk][nt] = h;
        }
    bf16x8 w2h[2], w2l[2];       // n = lc (<8), split hi/lo (3-pass)
#pragma unroll
    for (int kk = 0; kk < 2; ++kk) {
        bf16x8 h, l;
#pragma unroll
        for (int j = 0; j < 8; ++j) {
            int kidx = kk * 32 + lg * 8 + j;
            float v = (lc < 8) ? w2[kidx * 8 + lc] : 0.0f;
            __bf16 hb = (__bf16)v;
            h[j] = hb; l[j] = (__bf16)(v - (float)hb);
        }
        w2h[kk] = h; w2l[kk] = l;
    }
    bf16x8 wph[4];               // n = lc (<8), bf16-rounded (2-pass)
#pragma unroll
    for (int kk = 0; kk < 4; ++kk) {
        bf16x8 h;
#pragma unroll
        for (int j = 0; j < 8; ++j) {
            int kidx = kk * 32 + lg * 8 + j;
            h[j] = (lc < 8) ? (__bf16)wp[kidx * 8 + lc] : (__bf16)0.0f;
        }
        wph[kk] = h;
    }
    float b1v[4];
#pragma unroll
    for (int nt = 0; nt < 4; ++nt) b1v[nt] = b1[nt * 16 + lc];
    const float b2v = (lc < 8) ? b2[lc] : 0.0f;

    const int ntiles = (E + 63) >> 6;
    const int r0 = tid >> 4;   // 0..15 (x-load row)
    const int c8 = tid & 15;   // 8-float column chunk
    const int arow = wid * 16 + lc;   // this wave's A-frag row

    for (int tile = blockIdx.x; tile < ntiles; tile += gridDim.x) {
        const long long eb = (long long)tile * 64;

        // ---- Load x tile [64][128] f32, coalesced ----
        float4 vr[4][2];
#pragma unroll
        for (int it = 0; it < 4; ++it) {
            long long e = eb + r0 + it * 16;
            if (e > (long long)E - 1) e = E - 1;
            const float4* p = (const float4*)(x + (size_t)e * 128 + c8 * 8);
            vr[it][0] = p[0];
            vr[it][1] = p[1];
        }
        __syncthreads();   // barrier 1: everyone done reading XH(t-1)/HF(t-1)

        // ---- A: convert to split bf16, write LDS (swizzled) ----
#pragma unroll
        for (int it = 0; it < 4; ++it) {
            int row = r0 + it * 16;
            bf16x8 h, l;
            const float* f = (const float*)&vr[it][0];
#pragma unroll
            for (int j = 0; j < 8; ++j) {
                float v = f[j];
                __bf16 hb = (__bf16)v;
                h[j] = hb; l[j] = (__bf16)(v - (float)hb);
            }
            int off = swz(row, c8 * 16);
            *(bf16x8*)(XH + off) = h;
            *(bf16x8*)(XL + off) = l;
        }
        __syncthreads();   // barrier 2: x(t) visible to all waves

        // ---- D: read THIS WAVE's rows once; H = relu(x@w1+b1) for all 64 cols ----
        bf16x8 axh[4], axl[4];
#pragma unroll
        for (int kk = 0; kk < 4; ++kk) {
            int off = swz(arow, kk * 64 + lg * 16);
            axh[kk] = *(const bf16x8*)(XH + off);
            axl[kk] = *(const bf16x8*)(XL + off);
        }
        f32x4 acc[4] = {{0.f,0.f,0.f,0.f},{0.f,0.f,0.f,0.f},{0.f,0.f,0.f,0.f},{0.f,0.f,0.f,0.f}};
#pragma unroll
        for (int kk = 0; kk < 4; ++kk)
#pragma unroll
            for (int nt = 0; nt < 4; ++nt) {
                acc[nt] = MFMA(axh[kk], w1h[kk][nt], acc[nt]);
                acc[nt] = MFMA(axl[kk], w1h[kk][nt], acc[nt]);
            }
        // bias + relu -> HF (C-layout row = wid*16 + lg*4 + r: SAME WAVE reads it back)
#pragma unroll
        for (int nt = 0; nt < 4; ++nt)
#pragma unroll
            for (int r = 0; r < 4; ++r) {
                float hv = fmaxf(acc[nt][r] + b1v[nt], 0.f);
                int row = wid * 16 + lg * 4 + r;
                int col = nt * 16 + lc;
                *(float*)(HF + swz(row, col * 4)) = hv;
            }
        // no barrier: HF rows are private to this wave (compiler orders via lgkmcnt)

        // ---- F: logits = H@w2 + b2 (3-pass); scores = x@wp from kept A-frags ----
        f32x4 lac = {0.f, 0.f, 0.f, 0.f};
        f32x4 sac = {0.f, 0.f, 0.f, 0.f};
#pragma unroll
        for (int kk = 0; kk < 2; ++kk) {
            int base = kk * 128 + lg * 32;     // f32 bytes: k = kk*32 + lg*8
            f32x4 h0 = *(const f32x4*)(HF + swz(arow, base));
            f32x4 h1 = *(const f32x4*)(HF + swz(arow, base + 16));
            bf16x8 hh, hl;
#pragma unroll
            for (int j = 0; j < 4; ++j) {
                float v0 = h0[j]; __bf16 q0 = (__bf16)v0;
                hh[j] = q0; hl[j] = (__bf16)(v0 - (float)q0);
                float v1 = h1[j]; __bf16 q1 = (__bf16)v1;
                hh[j + 4] = q1; hl[j + 4] = (__bf16)(v1 - (float)q1);
            }
            lac = MFMA(hh, w2h[kk], lac);
            lac = MFMA(hl, w2h[kk], lac);
            lac = MFMA(hh, w2l[kk], lac);
        }
#pragma unroll
        for (int kk = 0; kk < 4; ++kk) {
            sac = MFMA(axh[kk], wph[kk], sac);
            sac = MFMA(axl[kk], wph[kk], sac);
        }

        // ---- Softmax over 8 cols (no max-sub; logits bounded) + fused dot ----
#pragma unroll
        for (int r = 0; r < 4; ++r) {
            float lv = lac[r] + b2v;           // TEMPERATURE = 1.0
            float p = __expf(lv);
            float s  = p;
            float fs = p * sac[r];
            s  += __shfl_xor(s, 1);  fs += __shfl_xor(fs, 1);
            s  += __shfl_xor(s, 2);  fs += __shfl_xor(fs, 2);
            s  += __shfl_xor(s, 4);  fs += __shfl_xor(fs, 4);
            float inv = 1.0f / s;
            float alpha = p * inv;
            float fv = fs * inv;
            long long edge = eb + wid * 16 + lg * 4 + r;
            if (edge < E) {
                if (lc < 8) outAlpha[edge * 8 + lc] = alpha;
                if (lc == 0) outFused[edge] = fv;
            }
        }
        // no end barrier: barrier 1 at next loop top orders XH/HF rewrite
    }
}

extern "C" void kernel_launch(void* const* d_in, const int* in_sizes, int n_in,
                              void* d_out, int out_size, void* d_ws, size_t ws_size,
                              hipStream_t stream) {
    const float* x  = (const float*)d_in[0];
    const float* w1 = (const float*)d_in[1];
    const float* b1 = (const float*)d_in[2];
    const float* w2 = (const float*)d_in[3];
    const float* b2 = (const float*)d_in[4];
    const float* wp = (const float*)d_in[5];

    const int E = in_sizes[0] / 128;
    float* outF = (float*)d_out;
    float* outA = outF + E;

    const int ntiles = (E + 63) >> 6;
    const int blocks = ntiles < 768 ? ntiles : 768;
    edge_moe_kernel<<<blocks, 256, 0, stream>>>(x, w1, b1, w2, b2, wp, outF, outA, E);
}

// Round 4
// 73.470 us; speedup vs baseline: 2.0074x; 2.0074x over previous
//
#include <hip/hip_runtime.h>
#include <hip/hip_bf16.h>

typedef __bf16 bf16x8 __attribute__((ext_vector_type(8)));
typedef float  f32x4  __attribute__((ext_vector_type(4)));

#define MFMA(a, b, c) __builtin_amdgcn_mfma_f32_16x16x32_bf16((a), (b), (c), 0, 0, 0)

// R4: R1's n-split skeleton (90.3us, no spills) minus fat.
//  - x stored bf16-only in LDS (16KB); the hi/lo split moved to the WEIGHT side
//    (w1h+w1l, w2h+w2l, wph+wpl in registers, built once). Error symmetric to
//    x-side split (x_lo@w vs x@w_lo, both ~6.5e-4 std on scores) - R3 confirmed
//    2-pass keeps absmax at 0.0039.
//  - phase D peels mt==wid first and stashes axh[kk] -> phase F scores MFMAs
//    reuse them; no x re-read.
//  - H goes through LDS f32 (cross-wave), converted once to bf16 (no hl),
//    2 MFMAs vs w2h/w2l.
//  - R3's softmax: no max-subtract (|logits|<~5), fused sum+dot, 6 shuffles/r.
// LDS 32KB (XH 16K + HF 16K) -> 3 blocks/CU; persistent VGPR ~96, peak ~155.

__device__ __forceinline__ int swz(int row, int byteInRow) {
    return row * 256 + (byteInRow ^ ((row & 7) << 4));
}

__global__ __launch_bounds__(256, 3) void edge_moe_kernel(
    const float* __restrict__ x,  const float* __restrict__ w1,
    const float* __restrict__ b1, const float* __restrict__ w2,
    const float* __restrict__ b2, const float* __restrict__ wp,
    float* __restrict__ outFused, float* __restrict__ outAlpha, int E)
{
    __shared__ __align__(16) char lds[32768];
    char* XH = lds;
    char* HF = lds + 16384;

    const int tid  = threadIdx.x;
    const int lane = tid & 63;
    const int wid  = tid >> 6;   // wave id 0..3 = H-col tile owner (n-split)
    const int lc   = lane & 15;
    const int lg   = lane >> 4;

    // ---- Weight B-fragments, split hi/lo on the WEIGHT side ----
    // B-frag (16x16x32): lane holds B[k = kk*32 + lg*8 + j][n], j=0..7.
    bf16x8 w1h[4], w1l[4];       // n = wid*16+lc (this wave's n-tile)
#pragma unroll
    for (int kk = 0; kk < 4; ++kk) {
        bf16x8 h, l;
#pragma unroll
        for (int j = 0; j < 8; ++j) {
            int kidx = kk * 32 + lg * 8 + j;
            float v = w1[kidx * 64 + wid * 16 + lc];
            __bf16 hb = (__bf16)v;
            h[j] = hb; l[j] = (__bf16)(v - (float)hb);
        }
        w1h[kk] = h; w1l[kk] = l;
    }
    bf16x8 w2h[2], w2l[2];       // n = lc (<8), padded 0
#pragma unroll
    for (int kk = 0; kk < 2; ++kk) {
        bf16x8 h, l;
#pragma unroll
        for (int j = 0; j < 8; ++j) {
            int kidx = kk * 32 + lg * 8 + j;
            float v = (lc < 8) ? w2[kidx * 8 + lc] : 0.0f;
            __bf16 hb = (__bf16)v;
            h[j] = hb; l[j] = (__bf16)(v - (float)hb);
        }
        w2h[kk] = h; w2l[kk] = l;
    }
    bf16x8 wph[4], wpl[4];       // n = lc (<8), padded 0
#pragma unroll
    for (int kk = 0; kk < 4; ++kk) {
        bf16x8 h, l;
#pragma unroll
        for (int j = 0; j < 8; ++j) {
            int kidx = kk * 32 + lg * 8 + j;
            float v = (lc < 8) ? wp[kidx * 8 + lc] : 0.0f;
            __bf16 hb = (__bf16)v;
            h[j] = hb; l[j] = (__bf16)(v - (float)hb);
        }
        wph[kk] = h; wpl[kk] = l;
    }
    const float b1v = b1[wid * 16 + lc];          // col fixed per wave (n-split)
    const float b2v = (lc < 8) ? b2[lc] : 0.0f;

    const int ntiles = (E + 63) >> 6;
    const int r0 = tid >> 4;          // 0..15 (x-load row)
    const int c8 = tid & 15;          // 8-float column chunk
    const int arow = wid * 16 + lc;   // this wave's phase-F A-frag row

    for (int tile = blockIdx.x; tile < ntiles; tile += gridDim.x) {
        const long long eb = (long long)tile * 64;

        // ---- Load x tile [64][128] f32, coalesced ----
        float4 vr[4][2];
#pragma unroll
        for (int it = 0; it < 4; ++it) {
            long long e = eb + r0 + it * 16;
            if (e > (long long)E - 1) e = E - 1;
            const float4* p = (const float4*)(x + (size_t)e * 128 + c8 * 8);
            vr[it][0] = p[0];
            vr[it][1] = p[1];
        }
        __syncthreads();   // barrier 1: XH(t-1)/HF(t-1) readers done

        // ---- A: convert to bf16 (hi only), write LDS (swizzled) ----
#pragma unroll
        for (int it = 0; it < 4; ++it) {
            int row = r0 + it * 16;
            bf16x8 h;
            const float* f = (const float*)&vr[it][0];
#pragma unroll
            for (int j = 0; j < 8; ++j) h[j] = (__bf16)f[j];
            *(bf16x8*)(XH + swz(row, c8 * 16)) = h;
        }
        __syncthreads();   // barrier 2: x(t) ready

        // ---- D: H = relu(x@w1+b1) for n-tile wid, all 4 m-tiles ----
        // Peel mtt=0 (mt = wid) and stash its A-frags for phase F's x@wp.
        bf16x8 axh[4];
        f32x4 acc[4] = {{0.f,0.f,0.f,0.f},{0.f,0.f,0.f,0.f},{0.f,0.f,0.f,0.f},{0.f,0.f,0.f,0.f}};
#pragma unroll
        for (int kk = 0; kk < 4; ++kk) {
            axh[kk] = *(const bf16x8*)(XH + swz(arow, kk * 64 + lg * 16));
            acc[0] = MFMA(axh[kk], w1h[kk], acc[0]);
            acc[0] = MFMA(axh[kk], w1l[kk], acc[0]);
        }
#pragma unroll
        for (int mtt = 1; mtt < 4; ++mtt) {
            const int mt = (wid + mtt) & 3;
            const int row = mt * 16 + lc;
#pragma unroll
            for (int kk = 0; kk < 4; ++kk) {
                bf16x8 ah = *(const bf16x8*)(XH + swz(row, kk * 64 + lg * 16));
                acc[mtt] = MFMA(ah, w1h[kk], acc[mtt]);
                acc[mtt] = MFMA(ah, w1l[kk], acc[mtt]);
            }
        }
        // bias + relu -> HF f32 (C-layout: row = mt*16+lg*4+r, col = wid*16+lc)
#pragma unroll
        for (int mtt = 0; mtt < 4; ++mtt) {
            const int mt = (wid + mtt) & 3;
#pragma unroll
            for (int r = 0; r < 4; ++r) {
                float hv = fmaxf(acc[mtt][r] + b1v, 0.f);
                *(float*)(HF + swz(mt * 16 + lg * 4 + r, (wid * 16 + lc) * 4)) = hv;
            }
        }
        __syncthreads();   // barrier 3: H ready (cross-wave)

        // ---- F: logits = H@w2 + b2 (H->bf16 once, w2 split); scores from axh ----
        f32x4 lac = {0.f, 0.f, 0.f, 0.f};
        f32x4 sac = {0.f, 0.f, 0.f, 0.f};
#pragma unroll
        for (int kk = 0; kk < 2; ++kk) {
            int base = kk * 128 + lg * 32;     // f32 bytes: k = kk*32 + lg*8
            f32x4 h0 = *(const f32x4*)(HF + swz(arow, base));
            f32x4 h1 = *(const f32x4*)(HF + swz(arow, base + 16));
            bf16x8 hh;
#pragma unroll
            for (int j = 0; j < 4; ++j) {
                hh[j]     = (__bf16)h0[j];
                hh[j + 4] = (__bf16)h1[j];
            }
            lac = MFMA(hh, w2h[kk], lac);
            lac = MFMA(hh, w2l[kk], lac);
        }
#pragma unroll
        for (int kk = 0; kk < 4; ++kk) {
            sac = MFMA(axh[kk], wph[kk], sac);
            sac = MFMA(axh[kk], wpl[kk], sac);
        }

        // ---- Softmax over 8 cols (lanes lc<8; no max-sub) + fused dot ----
#pragma unroll
        for (int r = 0; r < 4; ++r) {
            float lv = lac[r] + b2v;           // TEMPERATURE = 1.0
            float p = __expf(lv);
            float s  = p;
            float fs = p * sac[r];
            s  += __shfl_xor(s, 1);  fs += __shfl_xor(fs, 1);
            s  += __shfl_xor(s, 2);  fs += __shfl_xor(fs, 2);
            s  += __shfl_xor(s, 4);  fs += __shfl_xor(fs, 4);
            float inv = 1.0f / s;
            float alpha = p * inv;
            float fv = fs * inv;
            long long edge = eb + wid * 16 + lg * 4 + r;
            if (edge < E) {
                if (lc < 8) outAlpha[edge * 8 + lc] = alpha;
                if (lc == 0) outFused[edge] = fv;
            }
        }
        // loop-top barrier orders next tile's XH/HF overwrite
    }
}

extern "C" void kernel_launch(void* const* d_in, const int* in_sizes, int n_in,
                              void* d_out, int out_size, void* d_ws, size_t ws_size,
                              hipStream_t stream) {
    const float* x  = (const float*)d_in[0];
    const float* w1 = (const float*)d_in[1];
    const float* b1 = (const float*)d_in[2];
    const float* w2 = (const float*)d_in[3];
    const float* b2 = (const float*)d_in[4];
    const float* wp = (const float*)d_in[5];

    const int E = in_sizes[0] / 128;
    float* outF = (float*)d_out;
    float* outA = outF + E;

    const int ntiles = (E + 63) >> 6;
    const int blocks = ntiles < 768 ? ntiles : 768;
    edge_moe_kernel<<<blocks, 256, 0, stream>>>(x, w1, b1, w2, b2, wp, outF, outA, E);
}